// Round 1
// baseline (620.378 us; speedup 1.0000x reference)
//
#include <hip/hip_runtime.h>
#include <hip/hip_bf16.h>

#define VOCAB 2048
#define EMBD  256
#define LATD  64
#define TLEN  32
#define BATCH 64
#define NBLK  256

typedef __attribute__((ext_vector_type(8))) short bf16x8;
typedef __attribute__((ext_vector_type(4))) float f32x4;

// ---------------- init: out=1.5, c=0, h[0]=0 ----------------
__global__ void k_init(float* __restrict__ out, float* __restrict__ c,
                       ushort* __restrict__ h0) {
  int i = blockIdx.x * 256 + threadIdx.x;   // grid 512*256 = 131072
  out[i] = 1.5f;     // 64*32*64
  c[i]   = 0.f;      // 64*2048
  h0[i]  = 0;        // 64*2048 bf16 (parity 0)
}

// ---------- transpose+convert: src[K][8192] f32 -> dst[8192][K] bf16 ----------
__global__ void k_transpose(const float* __restrict__ src,
                            __hip_bfloat16* __restrict__ dst, int K) {
  __shared__ __hip_bfloat16 tile[64][72];
  int k0 = (blockIdx.x >> 7) * 64;
  int n0 = (blockIdx.x & 127) * 64;
  int tid = threadIdx.x;
  {
    int kl = tid >> 2;
    int nq = (tid & 3) << 4;
    const float* s = src + (size_t)(k0 + kl) * 8192 + n0 + nq;
#pragma unroll
    for (int i = 0; i < 4; ++i) {
      float4 v = *reinterpret_cast<const float4*>(s + i * 4);
      tile[nq + i * 4 + 0][kl] = __float2bfloat16(v.x);
      tile[nq + i * 4 + 1][kl] = __float2bfloat16(v.y);
      tile[nq + i * 4 + 2][kl] = __float2bfloat16(v.z);
      tile[nq + i * 4 + 3][kl] = __float2bfloat16(v.w);
    }
  }
  __syncthreads();
  {
    int nl = tid >> 2;
    int kq = (tid & 3) << 4;
    uint4* d = reinterpret_cast<uint4*>(dst + (size_t)(n0 + nl) * K + k0 + kq);
    const uint4* s = reinterpret_cast<const uint4*>(&tile[nl][kq]);
    d[0] = s[0];
    d[1] = s[1];
  }
}

// ---------- gather: xb[t*64+b][256] = bf16(emb[tokens[b][t]]) ----------
__global__ void k_gather(const int* __restrict__ tokens,
                         const float* __restrict__ emb,
                         __hip_bfloat16* __restrict__ xb) {
  int tid = threadIdx.x;
  int row = blockIdx.x * 4 + (tid >> 6);   // 512 blocks -> 2048 rows
  int lane = tid & 63;
  int t = row >> 6, b = row & 63;
  int tok = tokens[b * TLEN + t];
  float4 v = *reinterpret_cast<const float4*>(emb + (size_t)tok * EMBD + lane * 4);
  __hip_bfloat16* d = xb + (size_t)row * EMBD + lane * 4;
  d[0] = __float2bfloat16(v.x);
  d[1] = __float2bfloat16(v.y);
  d[2] = __float2bfloat16(v.z);
  d[3] = __float2bfloat16(v.w);
}

// ---------------- one recurrence step ----------------
// grid 256 blocks x 256 threads. Block j owns vocab cols v = j*8..j*8+7,
// i.e. z-cols gcol = gate*2048 + j*8 + vc for the 4 gates (i,f,g,o).
// Waves split K (2048 Wh + 256 Wx = 2304) -> no barriers in the K loop.
__global__ __launch_bounds__(256) void k_step(
    const int* __restrict__ tokens,
    const __hip_bfloat16* __restrict__ WhT,   // [8192][2048]
    const __hip_bfloat16* __restrict__ WxT,   // [8192][256]
    const __hip_bfloat16* __restrict__ xb,    // [2048][256] row = t*64+b
    const float* __restrict__ bias,           // [8192]
    __hip_bfloat16* __restrict__ hbuf,        // [2][64][2048]
    float* __restrict__ cbuf,                 // [64][2048]
    float* __restrict__ stats,                // [2][3][64][256]
    float* __restrict__ out,                  // [64][32][64]
    int t) {
  const int tid = threadIdx.x;
  const int lane = tid & 63;
  const int wid = tid >> 6;
  const int j = blockIdx.x;
  const int par = t & 1;
  const __hip_bfloat16* hcur = hbuf + par * (BATCH * VOCAB);
  __hip_bfloat16* hnext = hbuf + (par ^ 1) * (BATCH * VOCAB);

  __shared__ float racc[4][4][2][4][64];   // [wid][mf][nf][r][lane] 32KB
  __shared__ float sred[12];
  __shared__ float svalS;

  // ---- bounds output for step t (uses stats of h_t written last step) ----
  if (j < BATCH) {
    float val;
    if (t == 0) {
      int tok = tokens[j * TLEN];
      val = 1.5f * (2.f * tok + 1.f) * (1.f / 2048.f);
    } else {
      const float* st = stats + par * 3 * BATCH * NBLK;
      float a0 = st[(0 * BATCH + j) * NBLK + tid];
      float a1 = st[(1 * BATCH + j) * NBLK + tid];
      float a2 = st[(2 * BATCH + j) * NBLK + tid];
#pragma unroll
      for (int off = 32; off; off >>= 1) {
        a0 += __shfl_down(a0, off);
        a1 += __shfl_down(a1, off);
        a2 += __shfl_down(a2, off);
      }
      if (lane == 0) { sred[wid * 3] = a0; sred[wid * 3 + 1] = a1; sred[wid * 3 + 2] = a2; }
      __syncthreads();
      if (tid == 0) {
        float S  = sred[0] + sred[3] + sred[6] + sred[9];
        float SL = sred[1] + sred[4] + sred[7] + sred[10];
        float ST = sred[2] + sred[5] + sred[8] + sred[11];
        svalS = 1.5f * (2.f * SL + ST) / S;
      }
      __syncthreads();
      val = svalS;
    }
    if (tid >= t && tid < TLEN) out[(j * TLEN + tid) * LATD + t] = val;
  }

  // ---- GEMM: z[64 x 32cols] over K=2304, waves split K ----
  f32x4 acc[4][2];
#pragma unroll
  for (int mf = 0; mf < 4; ++mf)
#pragma unroll
    for (int nf = 0; nf < 2; ++nf) acc[mf][nf] = (f32x4){0.f, 0.f, 0.f, 0.f};

  const int rr = lane & 15;
  const int kg = lane >> 4;
  const int gcol0 = ((rr >> 3) << 11) + (j << 3) + (rr & 7);          // cols 0..15
  const int gcol1 = (((16 + rr) >> 3) << 11) + (j << 3) + (rr & 7);   // cols 16..31
  const __hip_bfloat16* xrow = xb + (size_t)t * BATCH * EMBD;

  for (int i = 0; i < 8; ++i) {            // this wave's 8 Wh chunks
    int k0 = (wid + 4 * i) * 64;
#pragma unroll
    for (int kk = 0; kk < 64; kk += 32) {
      int kb = k0 + kk + kg * 8;
      bf16x8 a0 = *(const bf16x8*)(hcur + (0 * 16 + rr) * VOCAB + kb);
      bf16x8 a1 = *(const bf16x8*)(hcur + (1 * 16 + rr) * VOCAB + kb);
      bf16x8 a2 = *(const bf16x8*)(hcur + (2 * 16 + rr) * VOCAB + kb);
      bf16x8 a3 = *(const bf16x8*)(hcur + (3 * 16 + rr) * VOCAB + kb);
      bf16x8 b0 = *(const bf16x8*)(WhT + (size_t)gcol0 * VOCAB + kb);
      bf16x8 b1 = *(const bf16x8*)(WhT + (size_t)gcol1 * VOCAB + kb);
      acc[0][0] = __builtin_amdgcn_mfma_f32_16x16x32_bf16(a0, b0, acc[0][0], 0, 0, 0);
      acc[0][1] = __builtin_amdgcn_mfma_f32_16x16x32_bf16(a0, b1, acc[0][1], 0, 0, 0);
      acc[1][0] = __builtin_amdgcn_mfma_f32_16x16x32_bf16(a1, b0, acc[1][0], 0, 0, 0);
      acc[1][1] = __builtin_amdgcn_mfma_f32_16x16x32_bf16(a1, b1, acc[1][1], 0, 0, 0);
      acc[2][0] = __builtin_amdgcn_mfma_f32_16x16x32_bf16(a2, b0, acc[2][0], 0, 0, 0);
      acc[2][1] = __builtin_amdgcn_mfma_f32_16x16x32_bf16(a2, b1, acc[2][1], 0, 0, 0);
      acc[3][0] = __builtin_amdgcn_mfma_f32_16x16x32_bf16(a3, b0, acc[3][0], 0, 0, 0);
      acc[3][1] = __builtin_amdgcn_mfma_f32_16x16x32_bf16(a3, b1, acc[3][1], 0, 0, 0);
    }
  }
  {                                        // this wave's Wx chunk (K 0..255)
    int k0 = wid * 64;
#pragma unroll
    for (int kk = 0; kk < 64; kk += 32) {
      int kb = k0 + kk + kg * 8;
      bf16x8 a0 = *(const bf16x8*)(xrow + (0 * 16 + rr) * EMBD + kb);
      bf16x8 a1 = *(const bf16x8*)(xrow + (1 * 16 + rr) * EMBD + kb);
      bf16x8 a2 = *(const bf16x8*)(xrow + (2 * 16 + rr) * EMBD + kb);
      bf16x8 a3 = *(const bf16x8*)(xrow + (3 * 16 + rr) * EMBD + kb);
      bf16x8 b0 = *(const bf16x8*)(WxT + (size_t)gcol0 * EMBD + kb);
      bf16x8 b1 = *(const bf16x8*)(WxT + (size_t)gcol1 * EMBD + kb);
      acc[0][0] = __builtin_amdgcn_mfma_f32_16x16x32_bf16(a0, b0, acc[0][0], 0, 0, 0);
      acc[0][1] = __builtin_amdgcn_mfma_f32_16x16x32_bf16(a0, b1, acc[0][1], 0, 0, 0);
      acc[1][0] = __builtin_amdgcn_mfma_f32_16x16x32_bf16(a1, b0, acc[1][0], 0, 0, 0);
      acc[1][1] = __builtin_amdgcn_mfma_f32_16x16x32_bf16(a1, b1, acc[1][1], 0, 0, 0);
      acc[2][0] = __builtin_amdgcn_mfma_f32_16x16x32_bf16(a2, b0, acc[2][0], 0, 0, 0);
      acc[2][1] = __builtin_amdgcn_mfma_f32_16x16x32_bf16(a2, b1, acc[2][1], 0, 0, 0);
      acc[3][0] = __builtin_amdgcn_mfma_f32_16x16x32_bf16(a3, b0, acc[3][0], 0, 0, 0);
      acc[3][1] = __builtin_amdgcn_mfma_f32_16x16x32_bf16(a3, b1, acc[3][1], 0, 0, 0);
    }
  }

  // ---- cross-wave K reduction ----
#pragma unroll
  for (int mf = 0; mf < 4; ++mf)
#pragma unroll
    for (int nf = 0; nf < 2; ++nf)
#pragma unroll
      for (int r = 0; r < 4; ++r) racc[wid][mf][nf][r][lane] = acc[mf][nf][r];
  __syncthreads();

  // ---- epilogue: wave w finishes rows wid*16..wid*16+15 ----
  const int s_ = (lane >> 3) & 1;
  const int vc = lane & 7;
  const int v = (j << 3) + vc;
  const float bias0 = bias[s_ * 2048 + v];        // frag0 gate: i (s=0) / f (s=1)
  const float bias1 = bias[(2 + s_) * 2048 + v];  // frag1 gate: g (s=0) / o (s=1)
  const int tnext = (t + 1 < TLEN) ? t + 1 : TLEN - 1;

  float e_[4], sl_[4], st_[4];
#pragma unroll
  for (int r = 0; r < 4; ++r) {
    int row = wid * 16 + kg * 4 + r;
    float z0 = racc[0][wid][0][r][lane] + racc[1][wid][0][r][lane] +
               racc[2][wid][0][r][lane] + racc[3][wid][0][r][lane] + bias0;
    float z1 = racc[0][wid][1][r][lane] + racc[1][wid][1][r][lane] +
               racc[2][wid][1][r][lane] + racc[3][wid][1][r][lane] + bias1;
    float o0 = __shfl_xor(z0, 8);
    float o1 = __shfl_xor(z1, 8);
    float zi = s_ ? o0 : z0;
    float zf = s_ ? z0 : o0;
    float zg = s_ ? o1 : z1;
    float zo = s_ ? z1 : o1;
    float cold = cbuf[row * VOCAB + v];
    float gi = 1.f / (1.f + __expf(-zi));
    float gf = 1.f / (1.f + __expf(-zf));
    float go = 1.f / (1.f + __expf(-zo));
    float cnew = gf * cold + gi * tanhf(zg);
    float hn = go * tanhf(cnew);
    if (!s_) {
      cbuf[row * VOCAB + v] = cnew;
      hnext[row * VOCAB + v] = __float2bfloat16(hn);
    }
    float e = __expf(hn);
    int tok = tokens[row * TLEN + tnext];
    e_[r] = e;
    sl_[r] = (v < tok) ? e : 0.f;
    st_[r] = (v == tok) ? e : 0.f;
  }
#pragma unroll
  for (int m = 1; m <= 4; m <<= 1)
#pragma unroll
    for (int r = 0; r < 4; ++r) {
      e_[r] += __shfl_xor(e_[r], m);
      sl_[r] += __shfl_xor(sl_[r], m);
      st_[r] += __shfl_xor(st_[r], m);
    }
  if (vc == 0 && s_ == 0) {
    float* stn = stats + (par ^ 1) * 3 * BATCH * NBLK;
#pragma unroll
    for (int r = 0; r < 4; ++r) {
      int row = wid * 16 + kg * 4 + r;
      stn[(0 * BATCH + row) * NBLK + j] = e_[r];
      stn[(1 * BATCH + row) * NBLK + j] = sl_[r];
      stn[(2 * BATCH + row) * NBLK + j] = st_[r];
    }
  }
}

extern "C" void kernel_launch(void* const* d_in, const int* in_sizes, int n_in,
                              void* d_out, int out_size, void* d_ws, size_t ws_size,
                              hipStream_t stream) {
  (void)in_sizes; (void)n_in; (void)out_size; (void)ws_size;
  const int* tokens = (const int*)d_in[0];
  const float* emb  = (const float*)d_in[1];
  const float* Wx   = (const float*)d_in[2];
  const float* Wh   = (const float*)d_in[3];
  const float* bias = (const float*)d_in[4];
  float* out = (float*)d_out;
  char* ws = (char*)d_ws;

  __hip_bfloat16* WhT = (__hip_bfloat16*)(ws);               // 33,554,432 B
  __hip_bfloat16* WxT = (__hip_bfloat16*)(ws + 33554432);    //  4,194,304 B
  __hip_bfloat16* xb  = (__hip_bfloat16*)(ws + 37748736);    //  1,048,576 B
  __hip_bfloat16* hb  = (__hip_bfloat16*)(ws + 38797312);    //    524,288 B
  float* cb           = (float*)(ws + 39321600);             //    524,288 B
  float* stats        = (float*)(ws + 39845888);             //    393,216 B

  k_init<<<512, 256, 0, stream>>>(out, cb, (ushort*)hb);
  k_transpose<<<4096, 256, 0, stream>>>(Wh, WhT, 2048);
  k_transpose<<<512, 256, 0, stream>>>(Wx, WxT, 256);
  k_gather<<<512, 256, 0, stream>>>(tokens, emb, xb);
  for (int t = 0; t < TLEN; ++t)
    k_step<<<NBLK, 256, 0, stream>>>(tokens, WhT, WxT, xb, bias, hb, cb, stats, out, t);
}

// Round 2
// 568.976 us; speedup vs baseline: 1.0903x; 1.0903x over previous
//
#include <hip/hip_runtime.h>
#include <hip/hip_bf16.h>

#define VOCAB 2048
#define EMBD  256
#define LATD  64
#define TLEN  32
#define BATCH 64
#define NBLK  256

typedef __attribute__((ext_vector_type(8))) short bf16x8;
typedef __attribute__((ext_vector_type(4))) float f32x4;

// ---------------- init: out=1.5, c=0, h[0]=0 ----------------
__global__ void k_init(float* __restrict__ out, float* __restrict__ c,
                       ushort* __restrict__ h0) {
  int i = blockIdx.x * 256 + threadIdx.x;   // grid 512*256 = 131072
  out[i] = 1.5f;     // 64*32*64
  c[i]   = 0.f;      // 64*2048
  h0[i]  = 0;        // 64*2048 bf16 (parity 0)
}

// ---------- transpose+convert: src[K][8192] f32 -> dst[8192][K] bf16 ----------
__global__ void k_transpose(const float* __restrict__ src,
                            __hip_bfloat16* __restrict__ dst, int K) {
  __shared__ __hip_bfloat16 tile[64][72];
  int k0 = (blockIdx.x >> 7) * 64;
  int n0 = (blockIdx.x & 127) * 64;
  int tid = threadIdx.x;
  {
    int kl = tid >> 2;
    int nq = (tid & 3) << 4;
    const float* s = src + (size_t)(k0 + kl) * 8192 + n0 + nq;
#pragma unroll
    for (int i = 0; i < 4; ++i) {
      float4 v = *reinterpret_cast<const float4*>(s + i * 4);
      tile[nq + i * 4 + 0][kl] = __float2bfloat16(v.x);
      tile[nq + i * 4 + 1][kl] = __float2bfloat16(v.y);
      tile[nq + i * 4 + 2][kl] = __float2bfloat16(v.z);
      tile[nq + i * 4 + 3][kl] = __float2bfloat16(v.w);
    }
  }
  __syncthreads();
  {
    int nl = tid >> 2;
    int kq = (tid & 3) << 4;
    uint4* d = reinterpret_cast<uint4*>(dst + (size_t)(n0 + nl) * K + k0 + kq);
    const uint4* s = reinterpret_cast<const uint4*>(&tile[nl][kq]);
    d[0] = s[0];
    d[1] = s[1];
  }
}

// ---------- gather: xb[t*64+b][256] = bf16(emb[tokens[b][t]]) ----------
__global__ void k_gather(const int* __restrict__ tokens,
                         const float* __restrict__ emb,
                         __hip_bfloat16* __restrict__ xb) {
  int tid = threadIdx.x;
  int row = blockIdx.x * 4 + (tid >> 6);   // 512 blocks -> 2048 rows
  int lane = tid & 63;
  int t = row >> 6, b = row & 63;
  int tok = tokens[b * TLEN + t];
  float4 v = *reinterpret_cast<const float4*>(emb + (size_t)tok * EMBD + lane * 4);
  __hip_bfloat16* d = xb + (size_t)row * EMBD + lane * 4;
  d[0] = __float2bfloat16(v.x);
  d[1] = __float2bfloat16(v.y);
  d[2] = __float2bfloat16(v.z);
  d[3] = __float2bfloat16(v.w);
}

// ---------------- one recurrence step ----------------
// grid 256 blocks x 512 threads (8 waves). Block j owns vocab cols
// v = j*8..j*8+7, i.e. z-cols gcol = gate*2048 + j*8 + vc for gates i,f,g,o.
// 8 waves split K (2048 Wh + 256 Wx) -> no barriers in the K loop.
// 512 threads => 2 waves/SIMD for latency hiding (was 1 at 256 threads).
__global__ __launch_bounds__(512) void k_step(
    const int* __restrict__ tokens,
    const __hip_bfloat16* __restrict__ WhT,   // [8192][2048]
    const __hip_bfloat16* __restrict__ WxT,   // [8192][256]
    const __hip_bfloat16* __restrict__ xb,    // [2048][256] row = t*64+b
    const float* __restrict__ bias,           // [8192]
    __hip_bfloat16* __restrict__ hbuf,        // [2][64][2048]
    float* __restrict__ cbuf,                 // [64][2048]
    float* __restrict__ stats,                // [2][3][64][256]
    float* __restrict__ out,                  // [64][32][64]
    int t) {
  const int tid = threadIdx.x;
  const int lane = tid & 63;
  const int wid = tid >> 6;                  // 0..7
  const int j = blockIdx.x;
  const int par = t & 1;
  const __hip_bfloat16* hcur = hbuf + par * (BATCH * VOCAB);
  __hip_bfloat16* hnext = hbuf + (par ^ 1) * (BATCH * VOCAB);

  __shared__ float racc[8][4][2][4][64];   // [wid][mf][nf][r][lane] 64KB
  __shared__ float sred[24];
  __shared__ float svalS;

  // ---- bounds output for step t (uses stats of h_t written last step) ----
  if (j < BATCH) {
    float val;
    if (t == 0) {
      int tok = tokens[j * TLEN];
      val = 1.5f * (2.f * tok + 1.f) * (1.f / 2048.f);
    } else {
      const float* st = stats + par * 3 * BATCH * NBLK;
      float a0 = 0.f, a1 = 0.f, a2 = 0.f;
      if (tid < NBLK) {
        a0 = st[(0 * BATCH + j) * NBLK + tid];
        a1 = st[(1 * BATCH + j) * NBLK + tid];
        a2 = st[(2 * BATCH + j) * NBLK + tid];
      }
#pragma unroll
      for (int off = 32; off; off >>= 1) {
        a0 += __shfl_down(a0, off);
        a1 += __shfl_down(a1, off);
        a2 += __shfl_down(a2, off);
      }
      if (lane == 0) { sred[wid * 3] = a0; sred[wid * 3 + 1] = a1; sred[wid * 3 + 2] = a2; }
      __syncthreads();
      if (tid == 0) {
        float S = 0.f, SL = 0.f, ST = 0.f;
#pragma unroll
        for (int w = 0; w < 4; ++w) {     // waves 4..7 loaded zeros
          S  += sred[w * 3];
          SL += sred[w * 3 + 1];
          ST += sred[w * 3 + 2];
        }
        svalS = 1.5f * (2.f * SL + ST) / S;
      }
      __syncthreads();
      val = svalS;
    }
    if (tid >= t && tid < TLEN) out[(j * TLEN + tid) * LATD + t] = val;
  }

  // ---- GEMM: z[64 x 32cols] over K=2304, 8 waves split K ----
  f32x4 acc[4][2];
#pragma unroll
  for (int mf = 0; mf < 4; ++mf)
#pragma unroll
    for (int nf = 0; nf < 2; ++nf) acc[mf][nf] = (f32x4){0.f, 0.f, 0.f, 0.f};

  const int rr = lane & 15;
  const int kg = lane >> 4;                 // 0..3 (K groups of 8)
  const int gcol0 = ((rr >> 3) << 11) + (j << 3) + (rr & 7);          // cols 0..15
  const int gcol1 = (((16 + rr) >> 3) << 11) + (j << 3) + (rr & 7);   // cols 16..31
  const __hip_bfloat16* xrow = xb + (size_t)t * BATCH * EMBD;

#pragma unroll
  for (int i = 0; i < 4; ++i) {            // this wave's 4 Wh chunks of 64
    int k0 = (wid + 8 * i) * 64;
#pragma unroll
    for (int kk = 0; kk < 64; kk += 32) {
      int kb = k0 + kk + kg * 8;
      bf16x8 a0 = *(const bf16x8*)(hcur + (0 * 16 + rr) * VOCAB + kb);
      bf16x8 a1 = *(const bf16x8*)(hcur + (1 * 16 + rr) * VOCAB + kb);
      bf16x8 a2 = *(const bf16x8*)(hcur + (2 * 16 + rr) * VOCAB + kb);
      bf16x8 a3 = *(const bf16x8*)(hcur + (3 * 16 + rr) * VOCAB + kb);
      bf16x8 b0 = *(const bf16x8*)(WhT + (size_t)gcol0 * VOCAB + kb);
      bf16x8 b1 = *(const bf16x8*)(WhT + (size_t)gcol1 * VOCAB + kb);
      acc[0][0] = __builtin_amdgcn_mfma_f32_16x16x32_bf16(a0, b0, acc[0][0], 0, 0, 0);
      acc[0][1] = __builtin_amdgcn_mfma_f32_16x16x32_bf16(a0, b1, acc[0][1], 0, 0, 0);
      acc[1][0] = __builtin_amdgcn_mfma_f32_16x16x32_bf16(a1, b0, acc[1][0], 0, 0, 0);
      acc[1][1] = __builtin_amdgcn_mfma_f32_16x16x32_bf16(a1, b1, acc[1][1], 0, 0, 0);
      acc[2][0] = __builtin_amdgcn_mfma_f32_16x16x32_bf16(a2, b0, acc[2][0], 0, 0, 0);
      acc[2][1] = __builtin_amdgcn_mfma_f32_16x16x32_bf16(a2, b1, acc[2][1], 0, 0, 0);
      acc[3][0] = __builtin_amdgcn_mfma_f32_16x16x32_bf16(a3, b0, acc[3][0], 0, 0, 0);
      acc[3][1] = __builtin_amdgcn_mfma_f32_16x16x32_bf16(a3, b1, acc[3][1], 0, 0, 0);
    }
  }
  {                                        // this wave's Wx chunk (32 of K=256)
    int kb = wid * 32 + kg * 8;
    bf16x8 a0 = *(const bf16x8*)(xrow + (0 * 16 + rr) * EMBD + kb);
    bf16x8 a1 = *(const bf16x8*)(xrow + (1 * 16 + rr) * EMBD + kb);
    bf16x8 a2 = *(const bf16x8*)(xrow + (2 * 16 + rr) * EMBD + kb);
    bf16x8 a3 = *(const bf16x8*)(xrow + (3 * 16 + rr) * EMBD + kb);
    bf16x8 b0 = *(const bf16x8*)(WxT + (size_t)gcol0 * EMBD + kb);
    bf16x8 b1 = *(const bf16x8*)(WxT + (size_t)gcol1 * EMBD + kb);
    acc[0][0] = __builtin_amdgcn_mfma_f32_16x16x32_bf16(a0, b0, acc[0][0], 0, 0, 0);
    acc[0][1] = __builtin_amdgcn_mfma_f32_16x16x32_bf16(a0, b1, acc[0][1], 0, 0, 0);
    acc[1][0] = __builtin_amdgcn_mfma_f32_16x16x32_bf16(a1, b0, acc[1][0], 0, 0, 0);
    acc[1][1] = __builtin_amdgcn_mfma_f32_16x16x32_bf16(a1, b1, acc[1][1], 0, 0, 0);
    acc[2][0] = __builtin_amdgcn_mfma_f32_16x16x32_bf16(a2, b0, acc[2][0], 0, 0, 0);
    acc[2][1] = __builtin_amdgcn_mfma_f32_16x16x32_bf16(a2, b1, acc[2][1], 0, 0, 0);
    acc[3][0] = __builtin_amdgcn_mfma_f32_16x16x32_bf16(a3, b0, acc[3][0], 0, 0, 0);
    acc[3][1] = __builtin_amdgcn_mfma_f32_16x16x32_bf16(a3, b1, acc[3][1], 0, 0, 0);
  }

  // ---- cross-wave K reduction ----
#pragma unroll
  for (int mf = 0; mf < 4; ++mf)
#pragma unroll
    for (int nf = 0; nf < 2; ++nf)
#pragma unroll
      for (int r = 0; r < 4; ++r) racc[wid][mf][nf][r][lane] = acc[mf][nf][r];
  __syncthreads();

  // ---- epilogue: wave pair (2m,2m+1) finishes fragment m; half splits r ----
  const int m = wid >> 1;                  // fragment 0..3
  const int half = wid & 1;                // r in {2*half, 2*half+1}
  const int s_ = (lane >> 3) & 1;
  const int vc = lane & 7;
  const int v = (j << 3) + vc;
  const float bias0 = bias[s_ * 2048 + v];        // frag0 gate: i (s=0) / f (s=1)
  const float bias1 = bias[(2 + s_) * 2048 + v];  // frag1 gate: g (s=0) / o (s=1)
  const int tnext = (t + 1 < TLEN) ? t + 1 : TLEN - 1;

  float e_[2], sl_[2], st_[2];
#pragma unroll
  for (int r2 = 0; r2 < 2; ++r2) {
    int r = half * 2 + r2;
    int row = m * 16 + kg * 4 + r;
    float z0 = bias0, z1 = bias1;
#pragma unroll
    for (int w = 0; w < 8; ++w) {
      z0 += racc[w][m][0][r][lane];
      z1 += racc[w][m][1][r][lane];
    }
    float o0 = __shfl_xor(z0, 8);
    float o1 = __shfl_xor(z1, 8);
    float zi = s_ ? o0 : z0;
    float zf = s_ ? z0 : o0;
    float zg = s_ ? o1 : z1;
    float zo = s_ ? z1 : o1;
    float cold = cbuf[row * VOCAB + v];
    float gi = 1.f / (1.f + __expf(-zi));
    float gf = 1.f / (1.f + __expf(-zf));
    float go = 1.f / (1.f + __expf(-zo));
    float cnew = gf * cold + gi * tanhf(zg);
    float hn = go * tanhf(cnew);
    if (!s_) {
      cbuf[row * VOCAB + v] = cnew;
      hnext[row * VOCAB + v] = __float2bfloat16(hn);
    }
    float e = __expf(hn);
    int tok = tokens[row * TLEN + tnext];
    e_[r2] = e;
    sl_[r2] = (v < tok) ? e : 0.f;
    st_[r2] = (v == tok) ? e : 0.f;
  }
#pragma unroll
  for (int mm = 1; mm <= 4; mm <<= 1)
#pragma unroll
    for (int r2 = 0; r2 < 2; ++r2) {
      e_[r2] += __shfl_xor(e_[r2], mm);
      sl_[r2] += __shfl_xor(sl_[r2], mm);
      st_[r2] += __shfl_xor(st_[r2], mm);
    }
  if (vc == 0 && s_ == 0) {
    float* stn = stats + (par ^ 1) * 3 * BATCH * NBLK;
#pragma unroll
    for (int r2 = 0; r2 < 2; ++r2) {
      int row = m * 16 + kg * 4 + half * 2 + r2;
      stn[(0 * BATCH + row) * NBLK + j] = e_[r2];
      stn[(1 * BATCH + row) * NBLK + j] = sl_[r2];
      stn[(2 * BATCH + row) * NBLK + j] = st_[r2];
    }
  }
}

extern "C" void kernel_launch(void* const* d_in, const int* in_sizes, int n_in,
                              void* d_out, int out_size, void* d_ws, size_t ws_size,
                              hipStream_t stream) {
  (void)in_sizes; (void)n_in; (void)out_size; (void)ws_size;
  const int* tokens = (const int*)d_in[0];
  const float* emb  = (const float*)d_in[1];
  const float* Wx   = (const float*)d_in[2];
  const float* Wh   = (const float*)d_in[3];
  const float* bias = (const float*)d_in[4];
  float* out = (float*)d_out;
  char* ws = (char*)d_ws;

  __hip_bfloat16* WhT = (__hip_bfloat16*)(ws);               // 33,554,432 B
  __hip_bfloat16* WxT = (__hip_bfloat16*)(ws + 33554432);    //  4,194,304 B
  __hip_bfloat16* xb  = (__hip_bfloat16*)(ws + 37748736);    //  1,048,576 B
  __hip_bfloat16* hb  = (__hip_bfloat16*)(ws + 38797312);    //    524,288 B
  float* cb           = (float*)(ws + 39321600);             //    524,288 B
  float* stats        = (float*)(ws + 39845888);             //    393,216 B

  k_init<<<512, 256, 0, stream>>>(out, cb, (ushort*)hb);
  k_transpose<<<4096, 256, 0, stream>>>(Wh, WhT, 2048);
  k_transpose<<<512, 256, 0, stream>>>(Wx, WxT, 256);
  k_gather<<<512, 256, 0, stream>>>(tokens, emb, xb);
  for (int t = 0; t < TLEN; ++t)
    k_step<<<NBLK, 512, 0, stream>>>(tokens, WhT, WxT, xb, bias, hb, cb, stats, out, t);
}